// Round 9
// baseline (138.834 us; speedup 1.0000x reference)
//
#include <hip/hip_runtime.h>
#include <hip/hip_bf16.h>

#define B_    8
#define S_    4096
#define DIN   512
#define DOUT  64
#define NROWS (B_ * S_)   // 32768

typedef __attribute__((ext_vector_type(8)))  short bf16x8;
typedef __attribute__((ext_vector_type(4)))  float f32x4;
typedef __attribute__((ext_vector_type(16))) float f32x16;
typedef __attribute__((ext_vector_type(2)))  unsigned int u32x2;
typedef __attribute__((ext_vector_type(2)))  int i32x2;

typedef const __attribute__((address_space(1))) unsigned int GUI;
typedef __attribute__((address_space(3))) unsigned int LUI;

__device__ __forceinline__ unsigned short f32_to_bf16(float f) {
    union { float f; unsigned int u; } c; c.f = f;
    unsigned int r = (c.u + 0x7FFFu + ((c.u >> 16) & 1u)) >> 16;
    return (unsigned short)r;
}
__device__ __forceinline__ float bf16_to_f32(unsigned short us) {
    union { unsigned int u; float f; } c; c.u = (unsigned int)us << 16;
    return c.f;
}

__device__ __forceinline__ float fast_exp2(float x) {
#if __has_builtin(__builtin_amdgcn_exp2f)
    return __builtin_amdgcn_exp2f(x);
#else
    return exp2f(x);
#endif
}

// combined reductions with partner lane^32 (semantics pinned by round-7 A/B:
// swap(X,Y) -> r.x = [X_lo|Y_lo], r.y = [X_hi|Y_hi])
__device__ __forceinline__ float max_xor32(float v) {
    i32x2 r = __builtin_amdgcn_permlane32_swap(__float_as_int(v), __float_as_int(v),
                                               false, false);
    return fmaxf(__int_as_float(r.x), __int_as_float(r.y));
}
__device__ __forceinline__ float sum_xor32(float v) {
    i32x2 r = __builtin_amdgcn_permlane32_swap(__float_as_int(v), __float_as_int(v),
                                               false, false);
    return __int_as_float(r.x) + __int_as_float(r.y);
}

// Rule-18 fence (see r6): LDS reads of the buffer COMPLETE before the barrier
#define LDS_READS_DONE_FENCE() do {                                   \
    asm volatile("s_waitcnt lgkmcnt(0)" ::: "memory");                \
    __builtin_amdgcn_sched_barrier(0);                                \
} while (0)

__device__ __forceinline__ int pidx_of(int tp, int j) {
    if (tp < 16) return tp - 8;                      // j==1
    if (tp < 24) return 8 + (tp - 16) * 2 + (j - 1); // j in {1,2}
    return 24 + (tp - 24) * 3 + (j - 1);             // j in {1,2,3}
}

// ---------------------------------------------------------------------------
// Kernel 1: W -> Wt2 bf16 B-frag order (unchanged from round 8).
// ---------------------------------------------------------------------------
__global__ void wt_convert(const float* __restrict__ WQ,
                           const float* __restrict__ WK,
                           const float* __restrict__ WV,
                           unsigned short* __restrict__ Wt2) {
    int idx = blockIdx.x * 256 + threadIdx.x;
    if (idx >= 3 * 512 * 16) return;
    int p   = idx / 8192;
    int rem = idx - p * 8192;
    int k   = rem >> 4;
    int n0  = (rem & 15) * 4;
    const float* W = (p == 0) ? WQ : ((p == 1) ? WK : WV);
    float4 v = *(const float4*)(W + k * 64 + n0);
    const int ks = k >> 5, kl = k & 31;
    float vv[4] = {v.x, v.y, v.z, v.w};
#pragma unroll
    for (int r = 0; r < 4; ++r) {
        int n = n0 + r;
        Wt2[(size_t)((ks * 12 + p * 4 + (n >> 4)) * 512) + (n & 15) * 32 + kl] =
            f32_to_bf16(vv[r]);
    }
}

// ---------------------------------------------------------------------------
// Kernel 2: fused QKV projection (unchanged from round 8 — proven correct).
// ---------------------------------------------------------------------------
__global__ __launch_bounds__(256) void qkv_proj(const float* __restrict__ x,
                                                const unsigned short* __restrict__ Wt2,
                                                unsigned short* __restrict__ QKV) {
    __shared__ alignas(16) float          xtile[2][1024];
    __shared__ alignas(16) unsigned short btile[2][6144];

    const int tid  = threadIdx.x;
    const int lane = tid & 63;
    const int wq   = tid >> 6;
    const int c15  = lane & 15;
    const int g    = lane >> 4;
    const float* xblk = x + (size_t)blockIdx.x * 32 * DIN;

    const int rw     = (wq & 1) * 16 + c15;
    const int nfbase = (wq >> 1) * 6;

    const int xrow = wq * 8 + (lane >> 3);
    const int xsl  = (lane & 7) ^ (xrow & 7);

    auto stage = [&](int slot, int ks) {
        __builtin_amdgcn_global_load_lds((GUI*)(xblk + ks * 32 + xrow * DIN + xsl * 4),
                                         (LUI*)((char*)&xtile[slot][0] + wq * 1024), 16, 0, 0);
        const unsigned short* Bs = Wt2 + (size_t)ks * 6144;
#pragma unroll
        for (int j = 0; j < 3; ++j)
            __builtin_amdgcn_global_load_lds((GUI*)(Bs + (j * 256 + tid) * 8),
                                             (LUI*)((char*)&btile[slot][0] + j * 4096 + wq * 1024),
                                             16, 0, 0);
    };
    stage(0, 0);
    stage(1, 1);

    f32x4 acc[6] = {};

    int cur = 0;
    for (int ks = 0; ks < 16; ++ks) {
        asm volatile("s_waitcnt vmcnt(4)" ::: "memory");
        asm volatile("s_barrier" ::: "memory");

        const char* xb = (const char*)&xtile[cur][0] + rw * 128;
        f32x4 a0 = *(const f32x4*)(xb + (((2 * g)     ^ (rw & 7)) << 4));
        f32x4 a1 = *(const f32x4*)(xb + (((2 * g + 1) ^ (rw & 7)) << 4));
        union { unsigned w[4]; bf16x8 v; } af;
        asm("v_cvt_pk_bf16_f32 %0, %1, %2" : "=v"(af.w[0]) : "v"(a0[0]), "v"(a0[1]));
        asm("v_cvt_pk_bf16_f32 %0, %1, %2" : "=v"(af.w[1]) : "v"(a0[2]), "v"(a0[3]));
        asm("v_cvt_pk_bf16_f32 %0, %1, %2" : "=v"(af.w[2]) : "v"(a1[0]), "v"(a1[1]));
        asm("v_cvt_pk_bf16_f32 %0, %1, %2" : "=v"(af.w[3]) : "v"(a1[2]), "v"(a1[3]));

        const char* bb = (const char*)&btile[cur][0] + c15 * 64 + g * 16;
#pragma unroll
        for (int n = 0; n < 6; ++n) {
            bf16x8 bf = *(const bf16x8*)(bb + (nfbase + n) * 1024);
            acc[n] = __builtin_amdgcn_mfma_f32_16x16x32_bf16(af.v, bf, acc[n], 0, 0, 0);
        }

        LDS_READS_DONE_FENCE();
        asm volatile("s_barrier" ::: "memory");
        {
            int tn = ks + 2; if (tn > 15) tn = 15;
            stage(cur, tn);
        }
        cur ^= 1;
    }
    asm volatile("s_waitcnt vmcnt(0)" ::: "memory");

    const int orow0 = blockIdx.x * 32 + (wq & 1) * 16 + g * 4;
#pragma unroll
    for (int n = 0; n < 6; ++n) {
        const int nfg  = nfbase + n;
        const int p    = nfg >> 2;
        const int ncol = (nfg & 3) * 16 + c15;
        if (p < 2) {
            unsigned short* outp = QKV + (size_t)p * NROWS * DOUT;
            const float sc = (p == 0) ? 0.125f * 1.44269504089f : 1.0f;
#pragma unroll
            for (int r = 0; r < 4; ++r)
                outp[(size_t)(orow0 + r) * DOUT + ncol] = f32_to_bf16(acc[n][r] * sc);
        } else {
            const int bb2  = orow0 >> 12;
            const int srow = orow0 & 4095;
            union { unsigned short s[4]; u32x2 d; } pk;
#pragma unroll
            for (int r = 0; r < 4; ++r) pk.s[r] = f32_to_bf16(acc[n][r]);
            *(u32x2*)(QKV + (size_t)2 * NROWS * DOUT +
                      ((size_t)bb2 * DOUT + ncol) * S_ + srow) = pk.d;
        }
    }
}

// ---------------------------------------------------------------------------
// Kernel 3: causal flash attention, 32x32 MFMA, S^T/O^T, in-register P (T12).
// Block = 128 q rows (4 waves x 32), KVBLK = 64, chunked split-KV (16 tiles).
// Grid 640 = 8 b x 80 chunks, all co-resident. LDS 32KB (no p_lds).
// ---------------------------------------------------------------------------
__global__ __launch_bounds__(256) void attn_fwd(const unsigned short* __restrict__ QKV,
                                                float* __restrict__ out,
                                                char* __restrict__ part1,
                                                float* __restrict__ ml0) {
    __shared__ alignas(16) unsigned short k_lds[2][4096]; // K[kv][d], swz slots
    __shared__ alignas(16) unsigned short v_lds[2][4096]; // V^T[d][kv], swz slots

    const int bid = blockIdx.x;
    const int b   = bid & 7;
    const int i   = bid >> 3;             // 0..79
    int tp, j;
    if      (i < 8)  { tp = i;                 j = 0; }
    else if (i < 24) { tp = 8 + ((i - 8) >> 1);  j = (i - 8) & 1; }
    else if (i < 48) { tp = 16 + (i - 24) / 3;   j = (i - 24) % 3; }
    else             { tp = 24 + ((i - 48) >> 2); j = (i - 48) & 3; }
    const int qb       = tp * 128;
    const int tile_lo  = 16 * j;
    const int tile_hi  = min(16 * j + 15, 2 * tp + 1);
    const int tile_cnt = tile_hi - tile_lo + 1;   // always >= 2

    const int tid  = threadIdx.x;
    const int lane = tid & 63;
    const int wq   = tid >> 6;
    const int q31  = lane & 31;
    const int h    = lane >> 5;
    const int swz  = q31 & 7;
    const int rb0  = q31 * 128;

    const unsigned short* Qg  = QKV + (size_t)b * S_ * DOUT;
    const unsigned short* Kg  = QKV + (size_t)NROWS * DOUT + (size_t)b * S_ * DOUT;
    const unsigned short* VTg = QKV + (size_t)2 * NROWS * DOUT + (size_t)b * DOUT * S_;

    // Q B-frags: lane (q31,h) holds Q[qrow][d = 16s + 8h + j], s = 0..3
    const int qrow = qb + wq * 32 + q31;
    const unsigned short* Qr = Qg + (size_t)qrow * DOUT + 8 * h;
    bf16x8 qf[4];
#pragma unroll
    for (int s = 0; s < 4; ++s) qf[s] = *(const bf16x8*)(Qr + 16 * s);
    asm volatile("s_waitcnt vmcnt(0)" ::: "memory");  // exact vmcnt bookkeeping

    const int i0 = wq * 128 + lane;
    const int i1 = i0 + 64;
    const int r0 = i0 >> 3, s0g = (i0 & 7) ^ (r0 & 7);
    const int r1 = i1 >> 3, s1g = (i1 & 7) ^ (r1 & 7);

    auto stage = [&](int slot, int tg) {
        const unsigned short* Kt = Kg + (size_t)tg * 64 * DOUT;
        const unsigned short* Vt = VTg + tg * 64;
        char* kbase = (char*)&k_lds[slot][0] + wq * 2048;
        char* vbase = (char*)&v_lds[slot][0] + wq * 2048;
        __builtin_amdgcn_global_load_lds((GUI*)(Kt + r0 * DOUT + s0g * 8), (LUI*)kbase, 16, 0, 0);
        __builtin_amdgcn_global_load_lds((GUI*)(Kt + r1 * DOUT + s1g * 8), (LUI*)(kbase + 1024), 16, 0, 0);
        __builtin_amdgcn_global_load_lds((GUI*)(Vt + (size_t)r0 * S_ + s0g * 8), (LUI*)vbase, 16, 0, 0);
        __builtin_amdgcn_global_load_lds((GUI*)(Vt + (size_t)r1 * S_ + s1g * 8), (LUI*)(vbase + 1024), 16, 0, 0);
    };

    stage(0, tile_lo);
    stage(1, tile_lo + (tile_cnt > 1 ? 1 : 0));

    f32x16 oacc0 = {}, oacc1 = {};
    float m_r = -3.0e38f, l_r = 0.f;

    int cur = 0;
    for (int itl = 0; itl < tile_cnt; ++itl) {
        const int tg = tile_lo + itl;
        asm volatile("s_waitcnt vmcnt(4)" ::: "memory");
        asm volatile("s_barrier" ::: "memory");

        const char* kb_ = (const char*)&k_lds[cur][0];
        const char* vb_ = (const char*)&v_lds[cur][0];

        // --- S^T = mfma(K, Q): lane (q31,h): S^T[kv = 32kb + c+8e+4h][q31] ---
        f32x16 sA = {}, sB = {};
#pragma unroll
        for (int s = 0; s < 4; ++s) {
            const int sl = ((2 * s + h) ^ swz) << 4;
            bf16x8 ka  = *(const bf16x8*)(kb_ + rb0 + sl);
            bf16x8 kb2 = *(const bf16x8*)(kb_ + rb0 + 4096 + sl);
            sA = __builtin_amdgcn_mfma_f32_32x32x16_bf16(ka,  qf[s], sA, 0, 0, 0);
            sB = __builtin_amdgcn_mfma_f32_32x32x16_bf16(kb2, qf[s], sB, 0, 0, 0);
        }

        // --- causal mask (only the last two tiles of the final chunk) ---
        if (tg >= 2 * tp) {
#pragma unroll
            for (int r2 = 0; r2 < 16; ++r2) {
                const int kvg = 64 * tg + (r2 & 3) + 8 * (r2 >> 2) + 4 * h;
                if (kvg      > qrow) sA[r2] = -1.0e30f;
                if (kvg + 32 > qrow) sB[r2] = -1.0e30f;
            }
        }

        // --- lane-local online softmax (q = q31; partner = lane^32) ---
        float t[16];
#pragma unroll
        for (int k2 = 0; k2 < 16; ++k2) t[k2] = fmaxf(sA[k2], sB[k2]);
#pragma unroll
        for (int st = 8; st >= 1; st >>= 1)
#pragma unroll
            for (int k2 = 0; k2 < st; ++k2) t[k2] = fmaxf(t[k2], t[k2 + st]);
        float mx = max_xor32(t[0]);
        const float mnew  = fmaxf(m_r, mx);
        const float alpha = fast_exp2(m_r - mnew);
        m_r = mnew;

#pragma unroll
        for (int k2 = 0; k2 < 16; ++k2) {
            sA[k2] = fast_exp2(sA[k2] - mnew);
            sB[k2] = fast_exp2(sB[k2] - mnew);
        }
#pragma unroll
        for (int k2 = 0; k2 < 16; ++k2) t[k2] = sA[k2] + sB[k2];
#pragma unroll
        for (int st = 8; st >= 1; st >>= 1)
#pragma unroll
            for (int k2 = 0; k2 < st; ++k2) t[k2] += t[k2 + st];
        l_r = l_r * alpha + sum_xor32(t[0]);

#pragma unroll
        for (int k2 = 0; k2 < 16; ++k2) { oacc0[k2] *= alpha; oacc1[k2] *= alpha; }

        // --- P pack (T12) + PV, per 16-kv step u; no LDS for P ---
        // j0-3 of the B-frag from partner-half h'=0 (regs e=2(u&1)+h_target),
        // j4-7 from h'=1; permlane32_swap(Pa,Pc) -> (w0,w2); (Pb,Pd) -> (w1,w3).
#define STEP_PV(u, Pv) do {                                                        \
        const int e0 = 2 * ((u) & 1);                                              \
        unsigned pa, pb2, pc, pd;                                                  \
        asm("v_cvt_pk_bf16_f32 %0, %1, %2" : "=v"(pa)  : "v"(Pv[4*e0+0]), "v"(Pv[4*e0+1])); \
        asm("v_cvt_pk_bf16_f32 %0, %1, %2" : "=v"(pb2) : "v"(Pv[4*e0+2]), "v"(Pv[4*e0+3])); \
        asm("v_cvt_pk_bf16_f32 %0, %1, %2" : "=v"(pc)  : "v"(Pv[4*e0+4]), "v"(Pv[4*e0+5])); \
        asm("v_cvt_pk_bf16_f32 %0, %1, %2" : "=v"(pd)  : "v"(Pv[4*e0+6]), "v"(Pv[4*e0+7])); \
        i32x2 ra = __builtin_amdgcn_permlane32_swap((int)pa,  (int)pc, false, false); \
        i32x2 rb = __builtin_amdgcn_permlane32_swap((int)pb2, (int)pd, false, false); \
        union { unsigned w[4]; bf16x8 v; } pw;                                     \
        pw.w[0] = (unsigned)ra.x; pw.w[1] = (unsigned)rb.x;                        \
        pw.w[2] = (unsigned)ra.y; pw.w[3] = (unsigned)rb.y;                        \
        const int slv = ((2 * (u) + h) ^ swz) << 4;                                \
        bf16x8 vfa = *(const bf16x8*)(vb_ + rb0 + slv);                            \
        bf16x8 vfb = *(const bf16x8*)(vb_ + rb0 + 4096 + slv);                     \
        oacc0 = __builtin_amdgcn_mfma_f32_32x32x16_bf16(vfa, pw.v, oacc0, 0, 0, 0);\
        oacc1 = __builtin_amdgcn_mfma_f32_32x32x16_bf16(vfb, pw.v, oacc1, 0, 0, 0);\
    } while (0)

        STEP_PV(0, sA); STEP_PV(1, sA); STEP_PV(2, sB); STEP_PV(3, sB);
#undef STEP_PV

        LDS_READS_DONE_FENCE();
        asm volatile("s_barrier" ::: "memory");
        {
            int tn = itl + 2; if (tn >= tile_cnt) tn = tile_cnt - 1;
            stage(cur, tile_lo + tn);
        }
        cur ^= 1;
    }

    asm volatile("s_waitcnt vmcnt(0)" ::: "memory");   // drain LDS-DMA pre-endpgm

    // O^T lane map: d = 32*db + (reg&3) + 8*(reg>>2) + 4*h, q = q31
    const int ql = wq * 32 + q31;
    if (j == 0 && tp < 8) {
        const float linv = 1.0f / l_r;
        float* op = out + (size_t)b * S_ * DOUT + (size_t)qrow * DOUT;
#pragma unroll
        for (int e = 0; e < 4; ++e) {
            f32x4 v0 = { oacc0[4*e+0]*linv, oacc0[4*e+1]*linv, oacc0[4*e+2]*linv, oacc0[4*e+3]*linv };
            f32x4 v1 = { oacc1[4*e+0]*linv, oacc1[4*e+1]*linv, oacc1[4*e+2]*linv, oacc1[4*e+3]*linv };
            *(f32x4*)(op + 8*e + 4*h)      = v0;
            *(f32x4*)(op + 32 + 8*e + 4*h) = v1;
        }
    } else if (j == 0) {
        float* op = out + (size_t)b * S_ * DOUT + (size_t)qrow * DOUT;
#pragma unroll
        for (int e = 0; e < 4; ++e) {
            f32x4 v0 = { oacc0[4*e+0], oacc0[4*e+1], oacc0[4*e+2], oacc0[4*e+3] };
            f32x4 v1 = { oacc1[4*e+0], oacc1[4*e+1], oacc1[4*e+2], oacc1[4*e+3] };
            *(f32x4*)(op + 8*e + 4*h)      = v0;
            *(f32x4*)(op + 32 + 8*e + 4*h) = v1;
        }
        if (h == 0) {
            float* ml = ml0 + (size_t)(b * 24 + (tp - 8)) * 256;
            ml[ql] = m_r; ml[128 + ql] = l_r;
        }
    } else {
        char* pb_ = part1 + (size_t)(b * 48 + pidx_of(tp, j)) * 17408;
        if (h == 0) {
            float* mf = (float*)pb_;
            mf[ql] = m_r; mf[128 + ql] = l_r;
        }
        unsigned short* ob = (unsigned short*)(pb_ + 1024);
#pragma unroll
        for (int e = 0; e < 4; ++e) {
            union { unsigned short s[4]; u32x2 d; } k0, k1;
#pragma unroll
            for (int c = 0; c < 4; ++c) { k0.s[c] = f32_to_bf16(oacc0[4*e+c]);
                                          k1.s[c] = f32_to_bf16(oacc1[4*e+c]); }
            *(u32x2*)(ob + (size_t)ql * 64 + 8*e + 4*h)      = k0.d;
            *(u32x2*)(ob + (size_t)ql * 64 + 32 + 8*e + 4*h) = k1.d;
        }
    }
}

// ---------------------------------------------------------------------------
// Kernel 4: combine KV-chunks for q-tiles tp>=8 (chunk0 unnormalized f32
// in-place in out; chunks j>=1 bf16 in part1). Grid 192 = 8 b x 24 tiles.
// ---------------------------------------------------------------------------
__global__ __launch_bounds__(256) void attn_reduce(float* __restrict__ out,
                                                   const char* __restrict__ part1,
                                                   const float* __restrict__ ml0) {
    const int b  = blockIdx.x / 24;
    const int tz = blockIdx.x % 24;
    const int tp = tz + 8;
    const int nc = (tp < 16) ? 2 : ((tp < 24) ? 3 : 4);

    float* otile = out + ((size_t)b * S_ + (size_t)tp * 128) * 64;
    const float* ml = ml0 + (size_t)(b * 24 + tz) * 256;
    const char* pbs[3];
    for (int jj = 1; jj < nc; ++jj)
        pbs[jj - 1] = part1 + (size_t)(b * 48 + pidx_of(tp, jj)) * 17408;

    const int d  = threadIdx.x & 63;
    const int qg = threadIdx.x >> 6;

    for (int q = qg; q < 128; q += 4) {
        float m = ml[q], l = ml[128 + q];
        float M = m;
        float mj[3], lj[3];
        for (int jj = 0; jj < nc - 1; ++jj) {
            const float* mf = (const float*)pbs[jj];
            mj[jj] = mf[q]; lj[jj] = mf[128 + q];
            M = fmaxf(M, mj[jj]);
        }
        float e0 = fast_exp2(m - M);
        float L  = e0 * l;
        float O  = e0 * otile[q * 64 + d];
        for (int jj = 0; jj < nc - 1; ++jj) {
            float ej = fast_exp2(mj[jj] - M);
            L += ej * lj[jj];
            unsigned short us = ((const unsigned short*)(pbs[jj] + 1024))[q * 64 + d];
            O += ej * bf16_to_f32(us);
        }
        otile[q * 64 + d] = O / L;
    }
}

// ---------------------------------------------------------------------------
extern "C" void kernel_launch(void* const* d_in, const int* in_sizes, int n_in,
                              void* d_out, int out_size, void* d_ws, size_t ws_size,
                              hipStream_t stream) {
    const float* x  = (const float*)d_in[0];
    const float* WQ = (const float*)d_in[1];
    const float* WK = (const float*)d_in[2];
    const float* WV = (const float*)d_in[3];

    unsigned short* Wt2   = (unsigned short*)d_ws;             // 192 KB
    unsigned short* QKV   = Wt2 + 192 * 512;                   // 12 MB: Q | K | V^T
    char*           part1 = (char*)d_ws + 12779520;            // 384 x 17408 B = 6.37 MB
    float*          ml0   = (float*)((char*)d_ws + 19464192);  // 192 KB

    wt_convert<<<96, 256, 0, stream>>>(WQ, WK, WV, Wt2);
    qkv_proj<<<1024, 256, 0, stream>>>(x, Wt2, QKV);
    attn_fwd<<<640, 256, 0, stream>>>(QKV, (float*)d_out, part1, ml0);
    attn_reduce<<<192, 256, 0, stream>>>((float*)d_out, part1, ml0);
}

// Round 10
// 77.089 us; speedup vs baseline: 1.8009x; 1.8009x over previous
//
#include <hip/hip_runtime.h>
#include <hip/hip_bf16.h>

#define B_    8
#define S_    4096
#define DIN   512
#define DOUT  64
#define NROWS (B_ * S_)   // 32768

typedef __attribute__((ext_vector_type(8)))  short bf16x8;
typedef __attribute__((ext_vector_type(4)))  float f32x4;
typedef __attribute__((ext_vector_type(16))) float f32x16;
typedef __attribute__((ext_vector_type(2)))  unsigned int u32x2;
typedef __attribute__((ext_vector_type(2)))  int i32x2;

typedef const __attribute__((address_space(1))) unsigned int GUI;
typedef __attribute__((address_space(3))) unsigned int LUI;

__device__ __forceinline__ unsigned short f32_to_bf16(float f) {
    union { float f; unsigned int u; } c; c.f = f;
    unsigned int r = (c.u + 0x7FFFu + ((c.u >> 16) & 1u)) >> 16;
    return (unsigned short)r;
}
__device__ __forceinline__ float bf16_to_f32(unsigned short us) {
    union { unsigned int u; float f; } c; c.u = (unsigned int)us << 16;
    return c.f;
}

__device__ __forceinline__ float fast_exp2(float x) {
#if __has_builtin(__builtin_amdgcn_exp2f)
    return __builtin_amdgcn_exp2f(x);
#else
    return exp2f(x);
#endif
}

// combined reductions with partner lane^32 (semantics pinned by round-7 A/B:
// swap(X,Y) -> r.x = [X_lo|Y_lo], r.y = [X_hi|Y_hi])
__device__ __forceinline__ float max_xor32(float v) {
    i32x2 r = __builtin_amdgcn_permlane32_swap(__float_as_int(v), __float_as_int(v),
                                               false, false);
    return fmaxf(__int_as_float(r.x), __int_as_float(r.y));
}
__device__ __forceinline__ float sum_xor32(float v) {
    i32x2 r = __builtin_amdgcn_permlane32_swap(__float_as_int(v), __float_as_int(v),
                                               false, false);
    return __int_as_float(r.x) + __int_as_float(r.y);
}

// Rule-18 fence (see r6): LDS reads of the buffer COMPLETE before the barrier
#define LDS_READS_DONE_FENCE() do {                                   \
    asm volatile("s_waitcnt lgkmcnt(0)" ::: "memory");                \
    __builtin_amdgcn_sched_barrier(0);                                \
} while (0)

__device__ __forceinline__ int pidx_of(int tp, int j) {
    if (tp < 16) return tp - 8;                      // j==1
    if (tp < 24) return 8 + (tp - 16) * 2 + (j - 1); // j in {1,2}
    return 24 + (tp - 24) * 3 + (j - 1);             // j in {1,2,3}
}

// ---------------------------------------------------------------------------
// Kernel 1: W -> Wt2 bf16 B-frag order (unchanged).
// ---------------------------------------------------------------------------
__global__ void wt_convert(const float* __restrict__ WQ,
                           const float* __restrict__ WK,
                           const float* __restrict__ WV,
                           unsigned short* __restrict__ Wt2) {
    int idx = blockIdx.x * 256 + threadIdx.x;
    if (idx >= 3 * 512 * 16) return;
    int p   = idx / 8192;
    int rem = idx - p * 8192;
    int k   = rem >> 4;
    int n0  = (rem & 15) * 4;
    const float* W = (p == 0) ? WQ : ((p == 1) ? WK : WV);
    float4 v = *(const float4*)(W + k * 64 + n0);
    const int ks = k >> 5, kl = k & 31;
    float vv[4] = {v.x, v.y, v.z, v.w};
#pragma unroll
    for (int r = 0; r < 4; ++r) {
        int n = n0 + r;
        Wt2[(size_t)((ks * 12 + p * 4 + (n >> 4)) * 512) + (n & 15) * 32 + kl] =
            f32_to_bf16(vv[r]);
    }
}

// ---------------------------------------------------------------------------
// Kernel 2: fused QKV projection (unchanged from round 8/9 — proven correct).
// ---------------------------------------------------------------------------
__global__ __launch_bounds__(256) void qkv_proj(const float* __restrict__ x,
                                                const unsigned short* __restrict__ Wt2,
                                                unsigned short* __restrict__ QKV) {
    __shared__ alignas(16) float          xtile[2][1024];
    __shared__ alignas(16) unsigned short btile[2][6144];

    const int tid  = threadIdx.x;
    const int lane = tid & 63;
    const int wq   = tid >> 6;
    const int c15  = lane & 15;
    const int g    = lane >> 4;
    const float* xblk = x + (size_t)blockIdx.x * 32 * DIN;

    const int rw     = (wq & 1) * 16 + c15;
    const int nfbase = (wq >> 1) * 6;

    const int xrow = wq * 8 + (lane >> 3);
    const int xsl  = (lane & 7) ^ (xrow & 7);

    auto stage = [&](int slot, int ks) {
        __builtin_amdgcn_global_load_lds((GUI*)(xblk + ks * 32 + xrow * DIN + xsl * 4),
                                         (LUI*)((char*)&xtile[slot][0] + wq * 1024), 16, 0, 0);
        const unsigned short* Bs = Wt2 + (size_t)ks * 6144;
#pragma unroll
        for (int j = 0; j < 3; ++j)
            __builtin_amdgcn_global_load_lds((GUI*)(Bs + (j * 256 + tid) * 8),
                                             (LUI*)((char*)&btile[slot][0] + j * 4096 + wq * 1024),
                                             16, 0, 0);
    };
    stage(0, 0);
    stage(1, 1);

    f32x4 acc[6] = {};

    int cur = 0;
    for (int ks = 0; ks < 16; ++ks) {
        asm volatile("s_waitcnt vmcnt(4)" ::: "memory");
        asm volatile("s_barrier" ::: "memory");

        const char* xb = (const char*)&xtile[cur][0] + rw * 128;
        f32x4 a0 = *(const f32x4*)(xb + (((2 * g)     ^ (rw & 7)) << 4));
        f32x4 a1 = *(const f32x4*)(xb + (((2 * g + 1) ^ (rw & 7)) << 4));
        union { unsigned w[4]; bf16x8 v; } af;
        asm("v_cvt_pk_bf16_f32 %0, %1, %2" : "=v"(af.w[0]) : "v"(a0[0]), "v"(a0[1]));
        asm("v_cvt_pk_bf16_f32 %0, %1, %2" : "=v"(af.w[1]) : "v"(a0[2]), "v"(a0[3]));
        asm("v_cvt_pk_bf16_f32 %0, %1, %2" : "=v"(af.w[2]) : "v"(a1[0]), "v"(a1[1]));
        asm("v_cvt_pk_bf16_f32 %0, %1, %2" : "=v"(af.w[3]) : "v"(a1[2]), "v"(a1[3]));

        const char* bb = (const char*)&btile[cur][0] + c15 * 64 + g * 16;
#pragma unroll
        for (int n = 0; n < 6; ++n) {
            bf16x8 bf = *(const bf16x8*)(bb + (nfbase + n) * 1024);
            acc[n] = __builtin_amdgcn_mfma_f32_16x16x32_bf16(af.v, bf, acc[n], 0, 0, 0);
        }

        LDS_READS_DONE_FENCE();
        asm volatile("s_barrier" ::: "memory");
        {
            int tn = ks + 2; if (tn > 15) tn = 15;
            stage(cur, tn);
        }
        cur ^= 1;
    }
    asm volatile("s_waitcnt vmcnt(0)" ::: "memory");

    const int orow0 = blockIdx.x * 32 + (wq & 1) * 16 + g * 4;
#pragma unroll
    for (int n = 0; n < 6; ++n) {
        const int nfg  = nfbase + n;
        const int p    = nfg >> 2;
        const int ncol = (nfg & 3) * 16 + c15;
        if (p < 2) {
            unsigned short* outp = QKV + (size_t)p * NROWS * DOUT;
            const float sc = (p == 0) ? 0.125f * 1.44269504089f : 1.0f;
#pragma unroll
            for (int r = 0; r < 4; ++r)
                outp[(size_t)(orow0 + r) * DOUT + ncol] = f32_to_bf16(acc[n][r] * sc);
        } else {
            const int bb2  = orow0 >> 12;
            const int srow = orow0 & 4095;
            union { unsigned short s[4]; u32x2 d; } pk;
#pragma unroll
            for (int r = 0; r < 4; ++r) pk.s[r] = f32_to_bf16(acc[n][r]);
            *(u32x2*)(QKV + (size_t)2 * NROWS * DOUT +
                      ((size_t)bb2 * DOUT + ncol) * S_ + srow) = pk.d;
        }
    }
}

// ---------------------------------------------------------------------------
// Kernel 3: causal flash attention, 32x32 MFMA, S^T/O^T, in-register P (T12).
// (unchanged from round 9 — proven correct)
// ---------------------------------------------------------------------------
__global__ __launch_bounds__(256) void attn_fwd(const unsigned short* __restrict__ QKV,
                                                float* __restrict__ out,
                                                char* __restrict__ part1,
                                                float* __restrict__ ml0) {
    __shared__ alignas(16) unsigned short k_lds[2][4096]; // K[kv][d], swz slots
    __shared__ alignas(16) unsigned short v_lds[2][4096]; // V^T[d][kv], swz slots

    const int bid = blockIdx.x;
    const int b   = bid & 7;
    const int i   = bid >> 3;             // 0..79
    int tp, j;
    if      (i < 8)  { tp = i;                 j = 0; }
    else if (i < 24) { tp = 8 + ((i - 8) >> 1);  j = (i - 8) & 1; }
    else if (i < 48) { tp = 16 + (i - 24) / 3;   j = (i - 24) % 3; }
    else             { tp = 24 + ((i - 48) >> 2); j = (i - 48) & 3; }
    const int qb       = tp * 128;
    const int tile_lo  = 16 * j;
    const int tile_hi  = min(16 * j + 15, 2 * tp + 1);
    const int tile_cnt = tile_hi - tile_lo + 1;   // always >= 2

    const int tid  = threadIdx.x;
    const int lane = tid & 63;
    const int wq   = tid >> 6;
    const int q31  = lane & 31;
    const int h    = lane >> 5;
    const int swz  = q31 & 7;
    const int rb0  = q31 * 128;

    const unsigned short* Qg  = QKV + (size_t)b * S_ * DOUT;
    const unsigned short* Kg  = QKV + (size_t)NROWS * DOUT + (size_t)b * S_ * DOUT;
    const unsigned short* VTg = QKV + (size_t)2 * NROWS * DOUT + (size_t)b * DOUT * S_;

    // Q B-frags: lane (q31,h) holds Q[qrow][d = 16s + 8h + j], s = 0..3
    const int qrow = qb + wq * 32 + q31;
    const unsigned short* Qr = Qg + (size_t)qrow * DOUT + 8 * h;
    bf16x8 qf[4];
#pragma unroll
    for (int s = 0; s < 4; ++s) qf[s] = *(const bf16x8*)(Qr + 16 * s);
    asm volatile("s_waitcnt vmcnt(0)" ::: "memory");  // exact vmcnt bookkeeping

    const int i0 = wq * 128 + lane;
    const int i1 = i0 + 64;
    const int r0 = i0 >> 3, s0g = (i0 & 7) ^ (r0 & 7);
    const int r1 = i1 >> 3, s1g = (i1 & 7) ^ (r1 & 7);

    auto stage = [&](int slot, int tg) {
        const unsigned short* Kt = Kg + (size_t)tg * 64 * DOUT;
        const unsigned short* Vt = VTg + tg * 64;
        char* kbase = (char*)&k_lds[slot][0] + wq * 2048;
        char* vbase = (char*)&v_lds[slot][0] + wq * 2048;
        __builtin_amdgcn_global_load_lds((GUI*)(Kt + r0 * DOUT + s0g * 8), (LUI*)kbase, 16, 0, 0);
        __builtin_amdgcn_global_load_lds((GUI*)(Kt + r1 * DOUT + s1g * 8), (LUI*)(kbase + 1024), 16, 0, 0);
        __builtin_amdgcn_global_load_lds((GUI*)(Vt + (size_t)r0 * S_ + s0g * 8), (LUI*)vbase, 16, 0, 0);
        __builtin_amdgcn_global_load_lds((GUI*)(Vt + (size_t)r1 * S_ + s1g * 8), (LUI*)(vbase + 1024), 16, 0, 0);
    };

    stage(0, tile_lo);
    stage(1, tile_lo + (tile_cnt > 1 ? 1 : 0));

    f32x16 oacc0 = {}, oacc1 = {};
    float m_r = -3.0e38f, l_r = 0.f;

    int cur = 0;
    for (int itl = 0; itl < tile_cnt; ++itl) {
        const int tg = tile_lo + itl;
        asm volatile("s_waitcnt vmcnt(4)" ::: "memory");
        asm volatile("s_barrier" ::: "memory");

        const char* kb_ = (const char*)&k_lds[cur][0];
        const char* vb_ = (const char*)&v_lds[cur][0];

        // --- S^T = mfma(K, Q): lane (q31,h): S^T[kv = 32kb + c+8e+4h][q31] ---
        f32x16 sA = {}, sB = {};
#pragma unroll
        for (int s = 0; s < 4; ++s) {
            const int sl = ((2 * s + h) ^ swz) << 4;
            bf16x8 ka  = *(const bf16x8*)(kb_ + rb0 + sl);
            bf16x8 kb2 = *(const bf16x8*)(kb_ + rb0 + 4096 + sl);
            sA = __builtin_amdgcn_mfma_f32_32x32x16_bf16(ka,  qf[s], sA, 0, 0, 0);
            sB = __builtin_amdgcn_mfma_f32_32x32x16_bf16(kb2, qf[s], sB, 0, 0, 0);
        }

        // --- causal mask (only the last two tiles of the final chunk) ---
        if (tg >= 2 * tp) {
#pragma unroll
            for (int r2 = 0; r2 < 16; ++r2) {
                const int kvg = 64 * tg + (r2 & 3) + 8 * (r2 >> 2) + 4 * h;
                if (kvg      > qrow) sA[r2] = -1.0e30f;
                if (kvg + 32 > qrow) sB[r2] = -1.0e30f;
            }
        }

        // --- lane-local online softmax (q = q31; partner = lane^32) ---
        float t[16];
#pragma unroll
        for (int k2 = 0; k2 < 16; ++k2) t[k2] = fmaxf(sA[k2], sB[k2]);
#pragma unroll
        for (int st = 8; st >= 1; st >>= 1)
#pragma unroll
            for (int k2 = 0; k2 < st; ++k2) t[k2] = fmaxf(t[k2], t[k2 + st]);
        float mx = max_xor32(t[0]);
        const float mnew  = fmaxf(m_r, mx);
        const float alpha = fast_exp2(m_r - mnew);
        m_r = mnew;

#pragma unroll
        for (int k2 = 0; k2 < 16; ++k2) {
            sA[k2] = fast_exp2(sA[k2] - mnew);
            sB[k2] = fast_exp2(sB[k2] - mnew);
        }
#pragma unroll
        for (int k2 = 0; k2 < 16; ++k2) t[k2] = sA[k2] + sB[k2];
#pragma unroll
        for (int st = 8; st >= 1; st >>= 1)
#pragma unroll
            for (int k2 = 0; k2 < st; ++k2) t[k2] += t[k2 + st];
        l_r = l_r * alpha + sum_xor32(t[0]);

#pragma unroll
        for (int k2 = 0; k2 < 16; ++k2) { oacc0[k2] *= alpha; oacc1[k2] *= alpha; }

        // --- P pack (T12) + PV, per 16-kv step u; no LDS for P ---
#define STEP_PV(u, Pv) do {                                                        \
        const int e0 = 2 * ((u) & 1);                                              \
        unsigned pa, pb2, pc, pd;                                                  \
        asm("v_cvt_pk_bf16_f32 %0, %1, %2" : "=v"(pa)  : "v"(Pv[4*e0+0]), "v"(Pv[4*e0+1])); \
        asm("v_cvt_pk_bf16_f32 %0, %1, %2" : "=v"(pb2) : "v"(Pv[4*e0+2]), "v"(Pv[4*e0+3])); \
        asm("v_cvt_pk_bf16_f32 %0, %1, %2" : "=v"(pc)  : "v"(Pv[4*e0+4]), "v"(Pv[4*e0+5])); \
        asm("v_cvt_pk_bf16_f32 %0, %1, %2" : "=v"(pd)  : "v"(Pv[4*e0+6]), "v"(Pv[4*e0+7])); \
        i32x2 ra = __builtin_amdgcn_permlane32_swap((int)pa,  (int)pc, false, false); \
        i32x2 rb = __builtin_amdgcn_permlane32_swap((int)pb2, (int)pd, false, false); \
        union { unsigned w[4]; bf16x8 v; } pw;                                     \
        pw.w[0] = (unsigned)ra.x; pw.w[1] = (unsigned)rb.x;                        \
        pw.w[2] = (unsigned)ra.y; pw.w[3] = (unsigned)rb.y;                        \
        const int slv = ((2 * (u) + h) ^ swz) << 4;                                \
        bf16x8 vfa = *(const bf16x8*)(vb_ + rb0 + slv);                            \
        bf16x8 vfb = *(const bf16x8*)(vb_ + rb0 + 4096 + slv);                     \
        oacc0 = __builtin_amdgcn_mfma_f32_32x32x16_bf16(vfa, pw.v, oacc0, 0, 0, 0);\
        oacc1 = __builtin_amdgcn_mfma_f32_32x32x16_bf16(vfb, pw.v, oacc1, 0, 0, 0);\
    } while (0)

        STEP_PV(0, sA); STEP_PV(1, sA); STEP_PV(2, sB); STEP_PV(3, sB);
#undef STEP_PV

        LDS_READS_DONE_FENCE();
        asm volatile("s_barrier" ::: "memory");
        {
            int tn = itl + 2; if (tn >= tile_cnt) tn = tile_cnt - 1;
            stage(cur, tile_lo + tn);
        }
        cur ^= 1;
    }

    asm volatile("s_waitcnt vmcnt(0)" ::: "memory");   // drain LDS-DMA pre-endpgm

    // O^T lane map: d = 32*db + (reg&3) + 8*(reg>>2) + 4*h, q = q31
    const int ql = wq * 32 + q31;
    if (j == 0 && tp < 8) {
        const float linv = 1.0f / l_r;
        float* op = out + (size_t)b * S_ * DOUT + (size_t)qrow * DOUT;
#pragma unroll
        for (int e = 0; e < 4; ++e) {
            f32x4 v0 = { oacc0[4*e+0]*linv, oacc0[4*e+1]*linv, oacc0[4*e+2]*linv, oacc0[4*e+3]*linv };
            f32x4 v1 = { oacc1[4*e+0]*linv, oacc1[4*e+1]*linv, oacc1[4*e+2]*linv, oacc1[4*e+3]*linv };
            *(f32x4*)(op + 8*e + 4*h)      = v0;
            *(f32x4*)(op + 32 + 8*e + 4*h) = v1;
        }
    } else if (j == 0) {
        float* op = out + (size_t)b * S_ * DOUT + (size_t)qrow * DOUT;
#pragma unroll
        for (int e = 0; e < 4; ++e) {
            f32x4 v0 = { oacc0[4*e+0], oacc0[4*e+1], oacc0[4*e+2], oacc0[4*e+3] };
            f32x4 v1 = { oacc1[4*e+0], oacc1[4*e+1], oacc1[4*e+2], oacc1[4*e+3] };
            *(f32x4*)(op + 8*e + 4*h)      = v0;
            *(f32x4*)(op + 32 + 8*e + 4*h) = v1;
        }
        if (h == 0) {
            float* ml = ml0 + (size_t)(b * 24 + (tp - 8)) * 256;
            ml[ql] = m_r; ml[128 + ql] = l_r;
        }
    } else {
        char* pb_ = part1 + (size_t)(b * 48 + pidx_of(tp, j)) * 17408;
        if (h == 0) {
            float* mf = (float*)pb_;
            mf[ql] = m_r; mf[128 + ql] = l_r;
        }
        unsigned short* ob = (unsigned short*)(pb_ + 1024);
#pragma unroll
        for (int e = 0; e < 4; ++e) {
            union { unsigned short s[4]; u32x2 d; } k0, k1;
#pragma unroll
            for (int c = 0; c < 4; ++c) { k0.s[c] = f32_to_bf16(oacc0[4*e+c]);
                                          k1.s[c] = f32_to_bf16(oacc1[4*e+c]); }
            *(u32x2*)(ob + (size_t)ql * 64 + 8*e + 4*h)      = k0.d;
            *(u32x2*)(ob + (size_t)ql * 64 + 32 + 8*e + 4*h) = k1.d;
        }
    }
}

// ---------------------------------------------------------------------------
// Kernel 4: combine KV-chunks. Templated on NC so every array index is
// compile-time (rule #20: runtime-indexed arrays spill to scratch — r9's
// 69 us at VGPR_Count=12 was exactly that). One thread per output element.
// Grid 6144 = 8 b x 24 tp x 32 q-subtiles; 256 thr = 4 q x 64 d.
// ---------------------------------------------------------------------------
template<int NC>
__device__ __forceinline__ void reduce_body(int b, int tp, int q, int d,
                                            float* __restrict__ out,
                                            const char* __restrict__ part1,
                                            const float* __restrict__ ml0) {
    float* otile = out + ((size_t)b * S_ + (size_t)tp * 128) * 64;
    const float* ml = ml0 + (size_t)(b * 24 + (tp - 8)) * 256;

    float m = ml[q], l = ml[128 + q];
    float M = m;
    float mj[NC - 1], lj[NC - 1];
    const unsigned short* obs[NC - 1];
#pragma unroll
    for (int jj = 0; jj < NC - 1; ++jj) {
        const char* pb = part1 + (size_t)(b * 48 + pidx_of(tp, jj + 1)) * 17408;
        const float* mf = (const float*)pb;
        mj[jj] = mf[q]; lj[jj] = mf[128 + q];
        obs[jj] = (const unsigned short*)(pb + 1024);
        M = fmaxf(M, mj[jj]);
    }
    const float e0 = fast_exp2(m - M);
    float L = e0 * l;
    float O = e0 * otile[(size_t)q * 64 + d];
#pragma unroll
    for (int jj = 0; jj < NC - 1; ++jj) {
        const float ej = fast_exp2(mj[jj] - M);
        L += ej * lj[jj];
        O += ej * bf16_to_f32(obs[jj][(size_t)q * 64 + d]);
    }
    otile[(size_t)q * 64 + d] = O / L;
}

__global__ __launch_bounds__(256) void attn_reduce(float* __restrict__ out,
                                                   const char* __restrict__ part1,
                                                   const float* __restrict__ ml0) {
    const int bid = blockIdx.x;          // 0..6143
    const int sub = bid & 31;            // q-subtile (4 rows)
    const int tz  = (bid >> 5) % 24;
    const int b   = bid / (32 * 24);
    const int tp  = tz + 8;
    const int q   = sub * 4 + (threadIdx.x >> 6);
    const int d   = threadIdx.x & 63;

    if (tp < 16)      reduce_body<2>(b, tp, q, d, out, part1, ml0);
    else if (tp < 24) reduce_body<3>(b, tp, q, d, out, part1, ml0);
    else              reduce_body<4>(b, tp, q, d, out, part1, ml0);
}

// ---------------------------------------------------------------------------
extern "C" void kernel_launch(void* const* d_in, const int* in_sizes, int n_in,
                              void* d_out, int out_size, void* d_ws, size_t ws_size,
                              hipStream_t stream) {
    const float* x  = (const float*)d_in[0];
    const float* WQ = (const float*)d_in[1];
    const float* WK = (const float*)d_in[2];
    const float* WV = (const float*)d_in[3];

    unsigned short* Wt2   = (unsigned short*)d_ws;             // 192 KB
    unsigned short* QKV   = Wt2 + 192 * 512;                   // 12 MB: Q | K | V^T
    char*           part1 = (char*)d_ws + 12779520;            // 384 x 17408 B
    float*          ml0   = (float*)((char*)d_ws + 19464192);  // 192 KB

    wt_convert<<<96, 256, 0, stream>>>(WQ, WK, WV, Wt2);
    qkv_proj<<<1024, 256, 0, stream>>>(x, Wt2, QKV);
    attn_fwd<<<640, 256, 0, stream>>>(QKV, (float*)d_out, part1, ml0);
    attn_reduce<<<6144, 256, 0, stream>>>((float*)d_out, part1, ml0);
}